// Round 10
// baseline (50.210 us; speedup 1.0000x reference)
//
#include <hip/hip_runtime.h>

// out[f, t, lm, k] (F=512, T=1024, LM=12, K=8) fp32:
//   l = lm/4, m = lm%4, s = k+l ; t < s -> 0
//   fs = (f - s) & 511 ; o = fs*24 + k*3 + l
//   val = b[o] + sum_{tap} w[o*3+tap] * x[m, t-2+tap, fs]   (neg time taps = 0)
//
// Persistent block = (f, half-T). 1024 blocks x 256 thr (4 blocks/CU), each runs
// 8 tiles of 64 t. Double-buffered LDS x-slab; per tile: {issue next tile's
// global loads to regs} -> {compute+dense-store current} -> {ds_write next} ->
// one __syncthreads. w/b staged once per block. Store phase = round 6's flat
// float4 chunks: every wave store instr is 1024 B dense.
// x slab: x_lds[m][tt][fi], fi=0..9 <-> fs=(f-9+fi)&511, tt=0..65 <-> t0-2+tt.
// XM=668 (==28 mod 32). Staging offsets precomputed: goff = (tt-2)*512+fs,
// pk = (ldsoff<<2)|m ; per tile g = goff + t0*512 (+ m<<19), g<0 -> 0.

typedef float f32x4 __attribute__((ext_vector_type(4)));

#define NF 512
#define NT 1024
#define TT 64
#define XROW 10
#define NROWS 66
#define XM 668            // 660 + 8 pad; %32==28, multiple of 4
#define SLAB (4 * XM)     // 2672
#define NSTG (4 * NROWS * XROW)  // 2640
#define NIT 11
#define DUMMY (SLAB - 1)  // unused pad slot

__global__ __launch_bounds__(256, 4) void caconv_kernel(
    const float* __restrict__ x,   // [4][1024][512]
    const float* __restrict__ w,   // [12288*3]
    const float* __restrict__ b,   // [12288]
    float* __restrict__ out)       // [512][1024][12][8]
{
    __shared__ float x_lds[2 * SLAB];   // 21.4 KB
    __shared__ float w_lds[72];         // [l][tap][k]
    __shared__ float b_lds[24];         // [l][k]

    const int tid   = threadIdx.x;
    const int f     = blockIdx.x >> 1;
    const int tbase = (blockIdx.x & 1) << 9;

    // ---- stage w (as [l][tap][k]) and b ([l][k]) once per block ----
    if (tid < 72) {
        const int l = tid / 24, rr = tid - l * 24, tap = rr >> 3, k = rr & 7;
        const int fs = (f - k - l + NF) & (NF - 1);
        w_lds[tid] = w[(fs * 24 + k * 3 + l) * 3 + tap];
    } else if (tid < 96) {
        const int jj = tid - 72, l = jj >> 3, k = jj & 7;
        const int fs = (f - k - l + NF) & (NF - 1);
        b_lds[jj] = b[fs * 24 + k * 3 + l];
    }

    // ---- precompute staging offsets (tile-invariant) ----
    int goff[NIT], pk[NIT];
#pragma unroll
    for (int it = 0; it < NIT; ++it) {
        const int i = tid + it * 256;
        if (i < NSTG) {
            const int fi = i % 10, row = i / 10;
            const int tt = row % 66, m = row / 66;
            const int fs = (f - 9 + fi + NF) & (NF - 1);
            goff[it] = ((tt - 2) << 9) + fs;                  // + t0*512 later
            pk[it]   = ((m * XM + tt * XROW + fi) << 2) | m;  // lds dword | m
        } else {
            goff[it] = -(1 << 30);   // forces g<0 -> v=0 -> DUMMY slot
            pk[it]   = DUMMY << 2;
        }
    }

    float r[NIT];

    // ---- prologue: stage tile 0 into buffer 0 ----
#pragma unroll
    for (int it = 0; it < NIT; ++it) {
        const int g = goff[it] + (tbase << 9);
        float v = 0.0f;
        if (g >= 0) v = x[g + ((pk[it] & 3) << 19)];
        r[it] = v;
    }
#pragma unroll
    for (int it = 0; it < NIT; ++it) x_lds[pk[it] >> 2] = r[it];
    __syncthreads();

    // chunk decode (tile-invariant start): c = tid + 256*cc, kh=c&1, q=c>>1
    const int k0     = (tid & 1) << 2;
    const int q0     = tid >> 1;
    const int t_off0 = q0 / 12;
    const int lm0    = q0 - t_off0 * 12;

#pragma unroll 1
    for (int j = 0; j < 8; ++j) {
        const int t0 = tbase + j * TT;
        const float* bufr = x_lds + (j & 1) * SLAB;
        float* bufw       = x_lds + ((j & 1) ^ 1) * SLAB;

        // issue next tile's loads early (latency hides under compute+stores)
        if (j < 7) {
            const int t1s = (t0 + TT) << 9;
#pragma unroll
            for (int it = 0; it < NIT; ++it) {
                const int g = goff[it] + t1s;
                float v = 0.0f;
                if (g >= 0) v = x[g + ((pk[it] & 3) << 19)];
                r[it] = v;
            }
        }

        // ---- compute + dense stores for tile j ----
        float* const outb = out + (size_t)((f << 10) + t0) * 96;
        int t_off = t_off0, lm = lm0;
#pragma unroll 1
        for (int c = 0; c < 6; ++c) {
            const int l = lm >> 2, m = lm & 3;

            const float* wp = w_lds + l * 24 + k0;
            const f32x4 w0 = *(const f32x4*)(wp);
            const f32x4 w1 = *(const f32x4*)(wp + 8);
            const f32x4 w2 = *(const f32x4*)(wp + 16);
            f32x4 acc = *(const f32x4*)(b_lds + l * 8 + k0);

            // fi = 6-l-k0+i  <->  k = k0+3-i
            const float* xp = bufr + m * XM + t_off * XROW + (6 - l - k0);
            {
                const float r0 = xp[0], r1 = xp[1], r2 = xp[2], r3 = xp[3];
                acc[0] += w0[0] * r3; acc[1] += w0[1] * r2;
                acc[2] += w0[2] * r1; acc[3] += w0[3] * r0;
            }
            {
                const float r0 = xp[10], r1 = xp[11], r2 = xp[12], r3 = xp[13];
                acc[0] += w1[0] * r3; acc[1] += w1[1] * r2;
                acc[2] += w1[2] * r1; acc[3] += w1[3] * r0;
            }
            {
                const float r0 = xp[20], r1 = xp[21], r2 = xp[22], r3 = xp[23];
                acc[0] += w2[0] * r3; acc[1] += w2[1] * r2;
                acc[2] += w2[2] * r1; acc[3] += w2[3] * r0;
            }

            if (t0 == 0 && t_off < 9) {   // zero guard: t < k + l
#pragma unroll
                for (int kk = 0; kk < 4; ++kk)
                    if (t_off < k0 + kk + l) acc[kk] = 0.0f;
            }

            *(f32x4*)(outb + (t_off * 12 + lm) * 8 + k0) = acc;

            lm += 8; t_off += 10;
            if (lm >= 12) { lm -= 12; ++t_off; }
        }

        // ---- write next tile into the other buffer, one barrier per tile ----
        if (j < 7) {
#pragma unroll
            for (int it = 0; it < NIT; ++it) bufw[pk[it] >> 2] = r[it];
            __syncthreads();
        }
    }
}

extern "C" void kernel_launch(void* const* d_in, const int* in_sizes, int n_in,
                              void* d_out, int out_size, void* d_ws, size_t ws_size,
                              hipStream_t stream)
{
    const float* x = (const float*)d_in[0];
    const float* w = (const float*)d_in[1];
    const float* b = (const float*)d_in[2];
    float* out = (float*)d_out;

    const int grid = NF * 2;   // 1024 persistent blocks (4 per CU)
    caconv_kernel<<<grid, 256, 0, stream>>>(x, w, b, out);
}

// Round 11
// 40.904 us; speedup vs baseline: 1.2275x; 1.2275x over previous
//
#include <hip/hip_runtime.h>

// out[f, t, lm, k] (F=512, T=1024, LM=12, K=8) fp32:
//   l = lm/4, m = lm%4, s = k+l ; t < s -> 0
//   fs = (f - s) & 511 ; o = fs*24 + k*3 + l
//   val = b[o] + sum_{tap} w[o*3+tap] * x[m, t-2+tap, fs]   (neg time taps = 0)
//
// Block = (8 features x 32 t), 192 threads, 2048 blocks (8/CU, all resident).
// Rationale: staging-read amplification drops from ~10x (1-f blocks) to 17/8,
// freeing L2/L3 read bandwidth that was contending with the 201 MB write stream.
// Slab: x_lds[m][tt][fi], fi=0..16 <-> feature (f0-9+fi)&511, tt=0..33 <-> t0-2+tt.
// XROW=17 (odd -> bank spread). Thread = (fl, lm, kh): fi base FIXED per thread
// = fl+6-l-4*kh; sliding 3-row register window over t: per iter 1 row load
// (4 dwords LDS), 12 FMA, 1 dense f32x4 store (runs of 24 lanes x 16B = 384 B
// contiguous per store instr, all full 64B sectors).
// w_lds[fl][l][tap][k] (576), b_lds[fl][l][k] (192): aligned b128 reads.

typedef float f32x4 __attribute__((ext_vector_type(4)));

#define NF 512
#define NT 1024
#define FB 8
#define TT 32
#define XROW 17
#define NROWS (TT + 2)        // 34
#define XM (NROWS * XROW)     // 578
#define SLAB (4 * XM)         // 2312

__global__ __launch_bounds__(192) void caconv_kernel(
    const float* __restrict__ x,   // [4][1024][512]
    const float* __restrict__ w,   // [12288*3]
    const float* __restrict__ b,   // [12288]
    float* __restrict__ out)       // [512][1024][12][8]
{
    __shared__ float x_lds[SLAB];      // 9.2 KB
    __shared__ float w_lds[FB * 72];   // [fl][l][tap][k]
    __shared__ float b_lds[FB * 24];   // [fl][l][k]

    const int tid = threadIdx.x;
    const int f0  = (blockIdx.x >> 5) * FB;
    const int t0  = (blockIdx.x & 31) * TT;

    // ---- stage w ([fl][l][tap][k]) and b ([fl][l][k]): 768 floats ----
    for (int i = tid; i < FB * 96; i += 192) {
        if (i < FB * 72) {
            const int fl = i / 72, r = i - fl * 72;
            const int l = r / 24, r2 = r - l * 24, tap = r2 >> 3, k = r2 & 7;
            const int fs = (f0 + fl - k - l + NF) & (NF - 1);
            w_lds[i] = w[(fs * 24 + k * 3 + l) * 3 + tap];
        } else {
            const int j = i - FB * 72;
            const int fl = j / 24, r = j - fl * 24, l = r >> 3, k = r & 7;
            const int fs = (f0 + fl - k - l + NF) & (NF - 1);
            b_lds[j] = b[fs * 24 + k * 3 + l];
        }
    }

    // ---- stage x slab: 4m x 34 rows x 17 fi = 2312 floats ----
    for (int i = tid; i < SLAB; i += 192) {
        const int fi  = i % XROW;
        const int row = i / XROW;
        const int tt  = row % NROWS;
        const int m   = row / NROWS;
        const int tg  = t0 - 2 + tt;
        const int fs  = (f0 - 9 + fi + NF) & (NF - 1);
        float v = 0.0f;
        if (tg >= 0) v = x[((m << 10) + tg) * NF + fs];
        x_lds[m * XM + tt * XROW + fi] = v;
    }
    __syncthreads();

    // ---- thread decode: fl (feature), lm, k-half ----
    const int fl = tid / 24;
    const int u  = tid - fl * 24;
    const int lm = u >> 1;
    const int k0 = (u & 1) << 2;
    const int l  = lm >> 2;
    const int m  = lm & 3;
    const int fib = fl + 6 - l - k0;     // fi of kk=3; fi(kk) = fib + 3 - kk

    const float* wp = w_lds + fl * 72 + l * 24 + k0;
    const f32x4 w0 = *(const f32x4*)(wp);
    const f32x4 w1 = *(const f32x4*)(wp + 8);
    const f32x4 w2 = *(const f32x4*)(wp + 16);
    const f32x4 bias = *(const f32x4*)(b_lds + fl * 24 + l * 8 + k0);

    const float* xp = x_lds + m * XM + fib;
    float* outp = out + ((size_t)(f0 + fl) * NT + t0) * 96 + lm * 8 + k0;

    // sliding 3-row window: rA=row(t_off), rB=row(t_off+1), rC=row(t_off+2)
    f32x4 rA, rB, rC;
    rA[0] = xp[0];  rA[1] = xp[1];  rA[2] = xp[2];  rA[3] = xp[3];
    rB[0] = xp[XROW]; rB[1] = xp[XROW+1]; rB[2] = xp[XROW+2]; rB[3] = xp[XROW+3];

#pragma unroll 4
    for (int t_off = 0; t_off < TT; ++t_off) {
        const float* rp = xp + (t_off + 2) * XROW;
        rC[0] = rp[0]; rC[1] = rp[1]; rC[2] = rp[2]; rC[3] = rp[3];

        f32x4 acc = bias;
        acc[0] += w0[0] * rA[3]; acc[1] += w0[1] * rA[2];
        acc[2] += w0[2] * rA[1]; acc[3] += w0[3] * rA[0];
        acc[0] += w1[0] * rB[3]; acc[1] += w1[1] * rB[2];
        acc[2] += w1[2] * rB[1]; acc[3] += w1[3] * rB[0];
        acc[0] += w2[0] * rC[3]; acc[1] += w2[1] * rC[2];
        acc[2] += w2[2] * rC[1]; acc[3] += w2[3] * rC[0];

        if (t0 == 0 && t_off < 10) {   // zero guard: t < k + l
#pragma unroll
            for (int kk = 0; kk < 4; ++kk)
                if (t_off < k0 + kk + l) acc[kk] = 0.0f;
        }

        *(f32x4*)outp = acc;
        outp += 96;

        rA = rB; rB = rC;
    }
}

extern "C" void kernel_launch(void* const* d_in, const int* in_sizes, int n_in,
                              void* d_out, int out_size, void* d_ws, size_t ws_size,
                              hipStream_t stream)
{
    const float* x = (const float*)d_in[0];
    const float* w = (const float*)d_in[1];
    const float* b = (const float*)d_in[2];
    float* out = (float*)d_out;

    const int grid = (NF / FB) * (NT / TT);   // 64 * 32 = 2048 blocks
    caconv_kernel<<<grid, 192, 0, stream>>>(x, w, b, out);
}